// Round 2
// baseline (307.446 us; speedup 1.0000x reference)
//
#include <hip/hip_runtime.h>

// RWKV chunked wkv recurrence, MI355X (gfx950).  T=32, H=4096, D=64.
// One wave (64 lanes) per head; lane i owns state row S[i][0..63] in VGPRs.
//
// Round-2 structure:
//  - k,r for ALL 32 steps staged into LDS in the prologue (16 KB/block);
//    main loop has NO barriers, NO ds_writes -> compiler can pipeline freely.
//  - v,td streamed with an explicit 2-deep rotating register prefetch
//    (no runtime-indexed register arrays -> no scratch, no AGPR splitting).
//  - out[i] = tf[i]*v[i]*(k.r) + sum_j S[i][j]*r[j]; the head-uniform dot
//    (k.r) is computed once per step via a 6-level shfl_xor reduce,
//    cutting the inner loop to 3 VALU per state element.

#define TT 32
#define HH 4096
#define DD 64

__global__ __launch_bounds__(64, 2)
void wkv_chunk_kernel(const float* __restrict__ k,
                      const float* __restrict__ v,
                      const float* __restrict__ r,
                      const float* __restrict__ state_in,
                      const float* __restrict__ td,
                      const float* __restrict__ tf,
                      float* __restrict__ out,        // [T,H,D]
                      float* __restrict__ state_out)  // [H,D,D]
{
    const int h    = blockIdx.x;   // one head per single-wave block
    const int lane = threadIdx.x;  // 0..63 = state row index i

    __shared__ __align__(16) float lk[TT][DD];
    __shared__ __align__(16) float lr[TT][DD];

    // ---- state row i -> 64 VGPRs ----
    float S[DD];
    {
        const float* sp = state_in + ((size_t)h * DD + lane) * DD;
        #pragma unroll
        for (int jq = 0; jq < DD / 4; ++jq) {
            const float4 s4 = reinterpret_cast<const float4*>(sp)[jq];
            S[4 * jq + 0] = s4.x;
            S[4 * jq + 1] = s4.y;
            S[4 * jq + 2] = s4.z;
            S[4 * jq + 3] = s4.w;
        }
    }
    const float tfi = tf[h * DD + lane];

    // ---- stage k,r for all 32 steps into LDS (chunks of 8 to bound VGPRs) ----
    {
        const size_t stp = (size_t)HH * DD;
        const float* kp = k + (size_t)h * DD + lane;
        const float* rp = r + (size_t)h * DD + lane;
        #pragma unroll
        for (int c = 0; c < TT / 8; ++c) {
            float kk[8], rr[8];
            #pragma unroll
            for (int u = 0; u < 8; ++u) {
                const int t = c * 8 + u;
                kk[u] = kp[t * stp];
                rr[u] = rp[t * stp];
            }
            #pragma unroll
            for (int u = 0; u < 8; ++u) {
                const int t = c * 8 + u;
                lk[t][lane] = kk[u];
                lr[t][lane] = rr[u];
            }
        }
    }
    __syncthreads();  // single wave: cheap; orders staging before reads

    // ---- v,td rotating 2-deep prefetch ----
    const size_t stp = (size_t)HH * DD;
    const float* vp = v  + (size_t)h * DD + lane;
    const float* tp = td + (size_t)h * DD + lane;
    float v0 = vp[0],   v1 = vp[stp];
    float d0 = tp[0],   d1 = tp[stp];

    for (int t = 0; t < TT; ++t) {
        const int tpre = (t + 2 < TT) ? (t + 2) : (TT - 1);  // clamped, branch-free
        const float v2 = vp[(size_t)tpre * stp];
        const float d2 = tp[(size_t)tpre * stp];

        // head-uniform dot(k_t, r_t): lane-local product + butterfly reduce
        float p = lk[t][lane] * lr[t][lane];
        #pragma unroll
        for (int m = 32; m >= 1; m >>= 1) p += __shfl_xor(p, m, 64);

        const float vi = v0, tdi = d0;

        float a0 = 0.f, a1 = 0.f, a2 = 0.f, a3 = 0.f;
        #pragma unroll
        for (int jq = 0; jq < DD / 4; ++jq) {
            const float4 k4 = *reinterpret_cast<const float4*>(&lk[t][4 * jq]);
            const float4 r4 = *reinterpret_cast<const float4*>(&lr[t][4 * jq]);
            a0 = fmaf(S[4 * jq + 0], r4.x, a0);
            S[4 * jq + 0] = fmaf(tdi, S[4 * jq + 0], vi * k4.x);
            a1 = fmaf(S[4 * jq + 1], r4.y, a1);
            S[4 * jq + 1] = fmaf(tdi, S[4 * jq + 1], vi * k4.y);
            a2 = fmaf(S[4 * jq + 2], r4.z, a2);
            S[4 * jq + 2] = fmaf(tdi, S[4 * jq + 2], vi * k4.z);
            a3 = fmaf(S[4 * jq + 3], r4.w, a3);
            S[4 * jq + 3] = fmaf(tdi, S[4 * jq + 3], vi * k4.w);
        }

        out[((size_t)t * HH + h) * DD + lane] =
            fmaf(tfi * vi, p, (a0 + a1) + (a2 + a3));

        v0 = v1; v1 = v2;
        d0 = d1; d1 = d2;
    }

    // ---- final state row ----
    {
        float* sp = state_out + ((size_t)h * DD + lane) * DD;
        #pragma unroll
        for (int jq = 0; jq < DD / 4; ++jq) {
            float4 s4;
            s4.x = S[4 * jq + 0];
            s4.y = S[4 * jq + 1];
            s4.z = S[4 * jq + 2];
            s4.w = S[4 * jq + 3];
            reinterpret_cast<float4*>(sp)[jq] = s4;
        }
    }
}

extern "C" void kernel_launch(void* const* d_in, const int* in_sizes, int n_in,
                              void* d_out, int out_size, void* d_ws, size_t ws_size,
                              hipStream_t stream) {
    const float* k     = (const float*)d_in[0];  // [T,H,1,D]
    const float* v     = (const float*)d_in[1];  // [T,H,D,1]
    const float* r     = (const float*)d_in[2];  // [T,H,D,1]
    const float* state = (const float*)d_in[3];  // [H,D,D]
    const float* td    = (const float*)d_in[4];  // [T,H,D,1]
    const float* tf    = (const float*)d_in[5];  // [H,D,1]

    float* out       = (float*)d_out;                         // [T,H,D]
    float* state_out = (float*)d_out + (size_t)TT * HH * DD;  // [H,D,D]

    wkv_chunk_kernel<<<dim3(HH), dim3(64), 0, stream>>>(
        k, v, r, state, td, tf, out, state_out);
}